// Round 5
// baseline (68.055 us; speedup 1.0000x reference)
//
#include <hip/hip_runtime.h>

#define H 256
#define W 256
#define OH 128
#define OW 128
#define RH 16   // output rows per wave strip; 8 strips (waves) = one plane = one block

typedef float vfloat2 __attribute__((ext_vector_type(2)));

// One wave (64 lanes x float4) covers a full 256-wide row.
// Rolling-register walk down the rows: h = horizontal [1,2,1] blur (shfl for
// neighbors), t = vertical [1,2,1] of h, eq4 = ((x - t/16)^2 + 1e-12)^(2|la|)+|al|,
// denom = 2x2 stride-1 avgpool of eq4 (edge-replicated), out = 2x2 stride-2
// avgpool of x*eq4/denom.
// 3-deep row prefetch keeps 2 global loads in flight per wave.
// One block = one plane (8 waves): strip halos are same-CU -> L2-local.

__device__ __forceinline__ float4 loadrow(const float* __restrict__ base, int r, int lane) {
    r = r < 0 ? 0 : (r > H - 1 ? H - 1 : r);
    return *reinterpret_cast<const float4*>(base + (size_t)r * W + 4 * lane);
}

__device__ __forceinline__ float4 hblur(const float4 v, int lane) {
    float left  = __shfl_up(v.w, 1);
    float right = __shfl_down(v.x, 1);
    left  = (lane == 0)  ? v.x : left;   // replicate pad col -1 -> col 0
    right = (lane == 63) ? v.w : right;  // replicate pad col 256 -> col 255
    float4 h;
    h.x = __fmaf_rn(2.f, v.x, left) + v.y;
    h.y = __fmaf_rn(2.f, v.y, v.x)  + v.z;
    h.z = __fmaf_rn(2.f, v.z, v.y)  + v.w;
    h.w = __fmaf_rn(2.f, v.w, v.z)  + right;
    return h;
}

// s^(2|la|) + |al|  ==  2^(2|la| * log2(s)) + |al|
// v_log_f32 / v_exp_f32 are natively base-2 on gfx9xx.
__device__ __forceinline__ float eq4s(float xv, float tv, float c2la, float al) {
    float d = __fmaf_rn(tv, -0.0625f, xv);     // x - blur
    float s = __fmaf_rn(d, d, 1e-12f);         // d^2 + eps^2
    return __builtin_amdgcn_exp2f(c2la * __builtin_amdgcn_logf(s)) + al;
}

__global__ __launch_bounds__(512)
void dp_rolling_kernel(const float* __restrict__ x,
                       const float* __restrict__ lamp,
                       const float* __restrict__ alphap,
                       float* __restrict__ out)
{
    const int wid   = threadIdx.x >> 6;
    const int lane  = threadIdx.x & 63;
    const int plane = blockIdx.x;                   // 0..1023 (b*C + c)
    const int strip = wid;                          // 0..7
    const int yb    = strip * RH;                   // output-row origin
    const int r0    = 2 * yb;                       // input-row origin

    const float* __restrict__ xp = x + (size_t)plane * (H * W);
    float* op = out + (size_t)plane * (OH * OW) + (size_t)yb * OW + 2 * lane;

    const float c2la = 2.f * fabsf(lamp[0]);
    const float al   = fabsf(alphap[0]);

    // rolling state (invariant at entry to step(r)):
    //   hm = h[r-1], hc = h[r], xc = x[r], xn = x[r+1], xn2 = x[r+2],
    //   ep = eq4[r-1], xe = x[r-1]
    float4 hm, hc, xc, xn, xn2, ep, xe;
    float accx = 0.f, accy = 0.f;

    // ---- prologue: compute eq4[r0] ----
    {
        float4 va = loadrow(xp, r0 - 1, lane);
        float4 vb = loadrow(xp, r0, lane);
        float4 vc = loadrow(xp, r0 + 1, lane);
        xn  = loadrow(xp, r0 + 2, lane);
        xn2 = loadrow(xp, r0 + 3, lane);
        float4 ha = hblur(va, lane);
        float4 hb = hblur(vb, lane);
        float4 hx = hblur(vc, lane);
        float4 t;
        t.x = __fmaf_rn(2.f, hb.x, ha.x) + hx.x;
        t.y = __fmaf_rn(2.f, hb.y, ha.y) + hx.y;
        t.z = __fmaf_rn(2.f, hb.z, ha.z) + hx.z;
        t.w = __fmaf_rn(2.f, hb.w, ha.w) + hx.w;
        ep.x = eq4s(vb.x, t.x, c2la, al);
        ep.y = eq4s(vb.y, t.y, c2la, al);
        ep.z = eq4s(vb.z, t.z, c2la, al);
        ep.w = eq4s(vb.w, t.w, c2la, al);
        xe = vb; hm = hb; hc = hx; xc = vc;
    }

    // finish: given ec = eq4[r], produce eq7 row r-1 contribution into acc
    auto finish = [&](const float4 ec) {
        float4 p;
        p.x = ep.x + ec.x; p.y = ep.y + ec.y;
        p.z = ep.z + ec.z; p.w = ep.w + ec.w;
        float pn = __shfl_down(p.x, 1);
        if (lane == 63) pn = p.w;                  // replicate pad col 256
        float d0 = __fmaf_rn(p.x + p.y, 0.25f, 1e-8f);
        float d1 = __fmaf_rn(p.y + p.z, 0.25f, 1e-8f);
        float d2 = __fmaf_rn(p.z + p.w, 0.25f, 1e-8f);
        float d3 = __fmaf_rn(p.w + pn,  0.25f, 1e-8f);
        accx += xe.x * ep.x * __builtin_amdgcn_rcpf(d0)
              + xe.y * ep.y * __builtin_amdgcn_rcpf(d1);
        accy += xe.z * ep.z * __builtin_amdgcn_rcpf(d2)
              + xe.w * ep.w * __builtin_amdgcn_rcpf(d3);
    };

    // full step at input row r (r <= H-1): compute eq4[r], finish row r-1
    auto stepT = [&](int r) {
        float4 xn3 = loadrow(xp, r + 3, lane);     // prefetch (clamped), 3 deep
        float4 hn  = hblur(xn, lane);              // h[r+1]
        float4 t;
        t.x = __fmaf_rn(2.f, hc.x, hm.x) + hn.x;
        t.y = __fmaf_rn(2.f, hc.y, hm.y) + hn.y;
        t.z = __fmaf_rn(2.f, hc.z, hm.z) + hn.z;
        t.w = __fmaf_rn(2.f, hc.w, hm.w) + hn.w;
        float4 ec;
        ec.x = eq4s(xc.x, t.x, c2la, al);
        ec.y = eq4s(xc.y, t.y, c2la, al);
        ec.z = eq4s(xc.z, t.z, c2la, al);
        ec.w = eq4s(xc.w, t.w, c2la, al);
        finish(ec);
        hm = hc; hc = hn; xe = xc; xc = xn; xn = xn2; xn2 = xn3; ep = ec;
    };

    int r = r0 + 1;
    for (int orr = 0; orr < RH - 1; ++orr) {
        stepT(r); ++r;
        stepT(r); ++r;
        vfloat2 o; o.x = accx * 0.25f; o.y = accy * 0.25f;
        __builtin_nontemporal_store(o, reinterpret_cast<vfloat2*>(op));
        op += OW;
        accx = 0.f; accy = 0.f;
    }
    // last output row of the strip: second step may be eq4 row 256 -> replicate
    stepT(r); ++r;
    if (r <= H - 1) {
        stepT(r);
    } else {
        finish(ep);                                // ec := ep (bottom replicate)
    }
    vfloat2 o; o.x = accx * 0.25f; o.y = accy * 0.25f;
    __builtin_nontemporal_store(o, reinterpret_cast<vfloat2*>(op));
}

extern "C" void kernel_launch(void* const* d_in, const int* in_sizes, int n_in,
                              void* d_out, int out_size, void* d_ws, size_t ws_size,
                              hipStream_t stream) {
    const float* x     = (const float*)d_in[0];
    const float* lam   = (const float*)d_in[1];
    const float* alpha = (const float*)d_in[2];
    float* out = (float*)d_out;

    // one block per plane: 8 waves x 16-output-row strips, halos L2-local
    dim3 grid(1024, 1, 1);
    dim3 block(512, 1, 1);
    dp_rolling_kernel<<<grid, block, 0, stream>>>(x, lam, alpha, out);
}

// Round 6
// 60.277 us; speedup vs baseline: 1.1290x; 1.1290x over previous
//
#include <hip/hip_runtime.h>

#define H 256
#define W 256
#define OH 128
#define OW 128
#define RH 16   // output rows per wave strip; 8 strips per plane

typedef float vfloat2 __attribute__((ext_vector_type(2)));

// One wave (64 lanes x float4) covers a full 256-wide row.
// Rolling-register walk down the rows: h = horizontal [1,2,1] blur (shfl for
// neighbors), t = vertical [1,2,1] of h, eq4 = ((x - t/16)^2 + 1e-12)^(2|la|)+|al|,
// denom = 2x2 stride-1 avgpool of eq4 (edge-replicated), out = 2x2 stride-2
// avgpool of x*eq4/denom.
// 3-deep row prefetch keeps 2 global loads in flight per wave.
// 2048 blocks x 256 threads (4 waves/block) benched best (round 4: 60.3 us);
// the 1-plane-per-512-thread-block variant regressed 13% (worse dispatch
// granularity / burstier traffic) — do not "improve" the layout again.

__device__ __forceinline__ float4 loadrow(const float* __restrict__ base, int r, int lane) {
    r = r < 0 ? 0 : (r > H - 1 ? H - 1 : r);
    return *reinterpret_cast<const float4*>(base + (size_t)r * W + 4 * lane);
}

__device__ __forceinline__ float4 hblur(const float4 v, int lane) {
    float left  = __shfl_up(v.w, 1);
    float right = __shfl_down(v.x, 1);
    left  = (lane == 0)  ? v.x : left;   // replicate pad col -1 -> col 0
    right = (lane == 63) ? v.w : right;  // replicate pad col 256 -> col 255
    float4 h;
    h.x = __fmaf_rn(2.f, v.x, left) + v.y;
    h.y = __fmaf_rn(2.f, v.y, v.x)  + v.z;
    h.z = __fmaf_rn(2.f, v.z, v.y)  + v.w;
    h.w = __fmaf_rn(2.f, v.w, v.z)  + right;
    return h;
}

// s^(2|la|) + |al|  ==  2^(2|la| * log2(s)) + |al|
// v_log_f32 / v_exp_f32 are natively base-2 on gfx9xx.
__device__ __forceinline__ float eq4s(float xv, float tv, float c2la, float al) {
    float d = __fmaf_rn(tv, -0.0625f, xv);     // x - blur
    float s = __fmaf_rn(d, d, 1e-12f);         // d^2 + eps^2
    return __builtin_amdgcn_exp2f(c2la * __builtin_amdgcn_logf(s)) + al;
}

__global__ __launch_bounds__(256)
void dp_rolling_kernel(const float* __restrict__ x,
                       const float* __restrict__ lamp,
                       const float* __restrict__ alphap,
                       float* __restrict__ out)
{
    const int wid   = threadIdx.x >> 6;
    const int lane  = threadIdx.x & 63;
    const int bid   = blockIdx.x;
    const int plane = bid >> 1;                     // 0..1023 (b*C + c)
    const int strip = ((bid & 1) << 2) | wid;       // 0..7
    const int yb    = strip * RH;                   // output-row origin
    const int r0    = 2 * yb;                       // input-row origin

    const float* __restrict__ xp = x + (size_t)plane * (H * W);
    float* op = out + (size_t)plane * (OH * OW) + (size_t)yb * OW + 2 * lane;

    const float c2la = 2.f * fabsf(lamp[0]);
    const float al   = fabsf(alphap[0]);

    // rolling state (invariant at entry to step(r)):
    //   hm = h[r-1], hc = h[r], xc = x[r], xn = x[r+1], xn2 = x[r+2],
    //   ep = eq4[r-1], xe = x[r-1]
    float4 hm, hc, xc, xn, xn2, ep, xe;
    float accx = 0.f, accy = 0.f;

    // ---- prologue: compute eq4[r0] ----
    {
        float4 va = loadrow(xp, r0 - 1, lane);
        float4 vb = loadrow(xp, r0, lane);
        float4 vc = loadrow(xp, r0 + 1, lane);
        xn  = loadrow(xp, r0 + 2, lane);
        xn2 = loadrow(xp, r0 + 3, lane);
        float4 ha = hblur(va, lane);
        float4 hb = hblur(vb, lane);
        float4 hx = hblur(vc, lane);
        float4 t;
        t.x = __fmaf_rn(2.f, hb.x, ha.x) + hx.x;
        t.y = __fmaf_rn(2.f, hb.y, ha.y) + hx.y;
        t.z = __fmaf_rn(2.f, hb.z, ha.z) + hx.z;
        t.w = __fmaf_rn(2.f, hb.w, ha.w) + hx.w;
        ep.x = eq4s(vb.x, t.x, c2la, al);
        ep.y = eq4s(vb.y, t.y, c2la, al);
        ep.z = eq4s(vb.z, t.z, c2la, al);
        ep.w = eq4s(vb.w, t.w, c2la, al);
        xe = vb; hm = hb; hc = hx; xc = vc;
    }

    // finish: given ec = eq4[r], produce eq7 row r-1 contribution into acc
    auto finish = [&](const float4 ec) {
        float4 p;
        p.x = ep.x + ec.x; p.y = ep.y + ec.y;
        p.z = ep.z + ec.z; p.w = ep.w + ec.w;
        float pn = __shfl_down(p.x, 1);
        if (lane == 63) pn = p.w;                  // replicate pad col 256
        float d0 = __fmaf_rn(p.x + p.y, 0.25f, 1e-8f);
        float d1 = __fmaf_rn(p.y + p.z, 0.25f, 1e-8f);
        float d2 = __fmaf_rn(p.z + p.w, 0.25f, 1e-8f);
        float d3 = __fmaf_rn(p.w + pn,  0.25f, 1e-8f);
        accx += xe.x * ep.x * __builtin_amdgcn_rcpf(d0)
              + xe.y * ep.y * __builtin_amdgcn_rcpf(d1);
        accy += xe.z * ep.z * __builtin_amdgcn_rcpf(d2)
              + xe.w * ep.w * __builtin_amdgcn_rcpf(d3);
    };

    // full step at input row r (r <= H-1): compute eq4[r], finish row r-1
    auto stepT = [&](int r) {
        float4 xn3 = loadrow(xp, r + 3, lane);     // prefetch (clamped), 3 deep
        float4 hn  = hblur(xn, lane);              // h[r+1]
        float4 t;
        t.x = __fmaf_rn(2.f, hc.x, hm.x) + hn.x;
        t.y = __fmaf_rn(2.f, hc.y, hm.y) + hn.y;
        t.z = __fmaf_rn(2.f, hc.z, hm.z) + hn.z;
        t.w = __fmaf_rn(2.f, hc.w, hm.w) + hn.w;
        float4 ec;
        ec.x = eq4s(xc.x, t.x, c2la, al);
        ec.y = eq4s(xc.y, t.y, c2la, al);
        ec.z = eq4s(xc.z, t.z, c2la, al);
        ec.w = eq4s(xc.w, t.w, c2la, al);
        finish(ec);
        hm = hc; hc = hn; xe = xc; xc = xn; xn = xn2; xn2 = xn3; ep = ec;
    };

    int r = r0 + 1;
    for (int orr = 0; orr < RH - 1; ++orr) {
        stepT(r); ++r;
        stepT(r); ++r;
        vfloat2 o; o.x = accx * 0.25f; o.y = accy * 0.25f;
        __builtin_nontemporal_store(o, reinterpret_cast<vfloat2*>(op));
        op += OW;
        accx = 0.f; accy = 0.f;
    }
    // last output row of the strip: second step may be eq4 row 256 -> replicate
    stepT(r); ++r;
    if (r <= H - 1) {
        stepT(r);
    } else {
        finish(ep);                                // ec := ep (bottom replicate)
    }
    vfloat2 o; o.x = accx * 0.25f; o.y = accy * 0.25f;
    __builtin_nontemporal_store(o, reinterpret_cast<vfloat2*>(op));
}

extern "C" void kernel_launch(void* const* d_in, const int* in_sizes, int n_in,
                              void* d_out, int out_size, void* d_ws, size_t ws_size,
                              hipStream_t stream) {
    const float* x     = (const float*)d_in[0];
    const float* lam   = (const float*)d_in[1];
    const float* alpha = (const float*)d_in[2];
    float* out = (float*)d_out;

    // 1024 planes x 8 strips of 16 output rows; 4 strips (waves) per block
    dim3 grid(2048, 1, 1);
    dim3 block(256, 1, 1);
    dp_rolling_kernel<<<grid, block, 0, stream>>>(x, lam, alpha, out);
}